// Round 2
// baseline (203.591 us; speedup 1.0000x reference)
//
#include <hip/hip_runtime.h>
#include <cstdint>
#include <cstddef>

// ---------------------------------------------------------------------------
// AxonalConnections: out[d] = sum_{s != d} x[s] @ W[p(s,d)]^T + bias[d]
//   x: [4, 2048, 1024] f32, W: [12, 1024, 1024] f32 (row o = out-dim, col i = in-dim)
//   bias[d][o] = strength[d] * (sin(t*local_freq[d][o]) + sin(t*global_freq[d]))
//   t = 2*pi*current_clk*0.001
// Strategy: fp16 MFMA grouped GEMM (no fp32 MFMA on CDNA4).
//   Per dst d: GEMM [2048, 3072] x [3072, 1024]^T (K = 3 src panels of 1024).
//   128x128 tile, BK=32, 4 waves (2x2 of 64x64), global_load_lds(16B),
//   double-buffered LDS with issue-early staging (T3-lite 2-phase schedule).
// ---------------------------------------------------------------------------

typedef _Float16 f16;
typedef _Float16 f16x8 __attribute__((ext_vector_type(8)));
typedef _Float16 f16x4 __attribute__((ext_vector_type(4)));
typedef float    f32x4 __attribute__((ext_vector_type(4)));

#define NMOD  4
#define BROWS 2048
#define DDIM  1024
#define BK    32
#define NT    96   // 3 src panels x 32 K-steps of BK=32

// ---- fp32 -> fp16 conversion, 4 elems/thread ----
__global__ void cvt_f32_f16(const float* __restrict__ in, f16* __restrict__ out, int n4) {
    int i = blockIdx.x * blockDim.x + threadIdx.x;
    if (i >= n4) return;
    float4 v = reinterpret_cast<const float4*>(in)[i];
    f16x4 h = { (f16)v.x, (f16)v.y, (f16)v.z, (f16)v.w };
    reinterpret_cast<f16x4*>(out)[i] = h;
}

// ---- bias table: bias[d][o] = st[d] * (sin(t*lf[d][o]) + sin(t*gf[d])) ----
__global__ void bias_kernel(const float* __restrict__ lf, const float* __restrict__ gf,
                            const float* __restrict__ st, const int* __restrict__ clk,
                            float* __restrict__ bias) {
    int d = blockIdx.x;
    int o = threadIdx.x;
    float t = (float)(6.283185307179586 * 0.001 * (double)(*clk));
    bias[d * DDIM + o] = st[d] * (sinf(t * lf[d * DDIM + o]) + sinf(t * gf[d]));
}

__device__ __forceinline__ void g2l16(const f16* g, f16* l) {
    // global -> LDS direct, 16B/lane; LDS dest is wave-uniform base (HW adds lane*16)
    __builtin_amdgcn_global_load_lds(
        (const __attribute__((address_space(1))) void*)g,
        (__attribute__((address_space(3))) void*)l,
        16, 0, 0);
}

__global__ __launch_bounds__(256, 2)
void gemm_kernel(const f16* __restrict__ X,     // [4, 2048, 1024] f16
                 const f16* __restrict__ Wh,    // [12, 1024, 1024] f16 (o-major = B^T)
                 const float* __restrict__ bias,// [4, 1024]
                 float* __restrict__ out) {     // [4, 2048, 1024] f32
    __shared__ f16 As[2][128 * BK];   // 2 x 8 KB
    __shared__ f16 Bs[2][128 * BK];   // 2 x 8 KB

    // 512 blocks: XCD-aware swizzle (512 % 8 == 0 -> bijective)
    const int bid = blockIdx.x;
    const int swz = ((bid & 7) << 6) + (bid >> 3);
    const int d  = swz >> 7;           // dst module 0..3
    const int m0 = ((swz >> 3) & 15) << 7;   // M tile origin (16 tiles)
    const int n0 = (swz & 7) << 7;           // N tile origin (8 tiles)

    const int t  = threadIdx.x;
    const int l  = t & 63;
    const int w  = t >> 6;            // wave 0..3
    const int wr = w >> 1;            // wave row (M)
    const int wc = w & 1;             // wave col (N)
    const int fr = l & 15;            // fragment row/col selector
    const int fq = l >> 4;            // k-group (A/B) / row-group (C)

    // staging geometry: wave w stages rows srow, srow+64; 32 cols; 64 lanes x 8 f16
    const int srow = (w << 4) + (l >> 2);   // 0..63 across 4 waves
    const int scol = (l & 3) << 3;          // 0,8,16,24

    f32x4 acc[4][4] = {};

    // stage K-tile tt into LDS buffer b (lane-linear order == row*BK+col order)
    auto stage = [&](int b, int tt) {
        const int j  = tt >> 5;                    // src panel 0..2 (uniform)
        const int k0 = (tt & 31) << 5;             // K offset within panel
        const int s  = j + (j >= d ? 1 : 0);       // src module (skip d)
        const int p  = s * 3 + d - (d > s ? 1 : 0);// index in PAIRS order
        const f16* xa = X  + ((size_t)s * BROWS + m0 + srow) * DDIM + k0 + scol;
        const f16* xb = Wh + ((size_t)p * DDIM  + n0 + srow) * DDIM + k0 + scol;
        f16* lA = &As[b][w << 9];   // wave-uniform base, 512 f16 per wave per call
        f16* lB = &Bs[b][w << 9];
        g2l16(xa,                     lA);
        g2l16(xa + (size_t)64 * DDIM, lA + 2048);
        g2l16(xb,                     lB);
        g2l16(xb + (size_t)64 * DDIM, lB + 2048);
    };

    auto compute = [&](int b) {
        f16x8 af[4], bf[4];
        #pragma unroll
        for (int m = 0; m < 4; ++m)
            af[m] = *reinterpret_cast<const f16x8*>(&As[b][(wr * 64 + m * 16 + fr) * BK + fq * 8]);
        #pragma unroll
        for (int n = 0; n < 4; ++n)
            bf[n] = *reinterpret_cast<const f16x8*>(&Bs[b][(wc * 64 + n * 16 + fr) * BK + fq * 8]);
        #pragma unroll
        for (int m = 0; m < 4; ++m)
            #pragma unroll
            for (int n = 0; n < 4; ++n)
                acc[m][n] = __builtin_amdgcn_mfma_f32_16x16x32_f16(af[m], bf[n], acc[m][n], 0, 0, 0);
    };

    // prologue: fill buf0
    stage(0, 0);
    __syncthreads();                 // vmcnt(0) drained -> buf0 ready

    // steady state: issue next stage early, compute current, one barrier per step
    #pragma unroll 1
    for (int tt = 0; tt < NT - 2; tt += 2) {
        stage(1, tt + 1);
        compute(0);
        __syncthreads();             // buf1 ready; all waves done reading buf0
        stage(0, tt + 2);
        compute(1);
        __syncthreads();             // buf0 ready; all waves done reading buf1
    }
    // tail: tt = NT-2
    stage(1, NT - 1);
    compute(0);
    __syncthreads();
    compute(1);

    // epilogue: C[row][col], col = lane&15, row = (lane>>4)*4 + reg  (+ fused bias)
    const int c0 = n0 + wc * 64 + fr;
    const int r0 = m0 + wr * 64 + fq * 4;
    float* od = out + (size_t)d * BROWS * DDIM;
    const float* bd = bias + d * DDIM;
    #pragma unroll
    for (int n = 0; n < 4; ++n) {
        const float bv = bd[c0 + n * 16];
        #pragma unroll
        for (int m = 0; m < 4; ++m) {
            #pragma unroll
            for (int r = 0; r < 4; ++r) {
                od[(size_t)(r0 + m * 16 + r) * DDIM + (c0 + n * 16)] = acc[m][n][r] + bv;
            }
        }
    }
}

// ---- insurance fallback (only if ws_size is too small for the fp16 path) ----
__global__ __launch_bounds__(256)
void gemm_f32_fallback(const float* __restrict__ X, const float* __restrict__ W,
                       const float* __restrict__ lf, const float* __restrict__ gf,
                       const float* __restrict__ st, const int* __restrict__ clk,
                       float* __restrict__ out) {
    const int d = blockIdx.y;
    const int b = blockIdx.x;
    __shared__ float xs[3][DDIM];
    for (int j = 0; j < 3; ++j) {
        int s = j + (j >= d ? 1 : 0);
        for (int i = threadIdx.x; i < DDIM; i += 256)
            xs[j][i] = X[((size_t)s * BROWS + b) * DDIM + i];
    }
    __syncthreads();
    float t = (float)(6.283185307179586 * 0.001 * (double)(*clk));
    for (int oi = 0; oi < 4; ++oi) {
        int o = threadIdx.x + oi * 256;
        float acc = 0.f;
        for (int j = 0; j < 3; ++j) {
            int s = j + (j >= d ? 1 : 0);
            int p = s * 3 + d - (d > s ? 1 : 0);
            const float* wrow = W + ((size_t)p * DDIM + o) * DDIM;
            float a = 0.f;
            for (int k = 0; k < DDIM; k += 4) {
                float4 wv = *reinterpret_cast<const float4*>(wrow + k);
                a += xs[j][k] * wv.x + xs[j][k + 1] * wv.y
                   + xs[j][k + 2] * wv.z + xs[j][k + 3] * wv.w;
            }
            acc += a;
        }
        out[((size_t)d * BROWS + b) * DDIM + o] =
            acc + st[d] * (sinf(t * lf[d * DDIM + o]) + sinf(t * gf[d]));
    }
}

extern "C" void kernel_launch(void* const* d_in, const int* in_sizes, int n_in,
                              void* d_out, int out_size, void* d_ws, size_t ws_size,
                              hipStream_t stream) {
    const float* x  = (const float*)d_in[0];   // [4,2048,1024]
    const float* W  = (const float*)d_in[1];   // [12,1024,1024]
    const float* lf = (const float*)d_in[2];   // [4,1024]
    const float* gf = (const float*)d_in[3];   // [4]
    const float* st = (const float*)d_in[4];   // [4]
    const int*  clk = (const int*)d_in[5];     // scalar
    float* out = (float*)d_out;

    const size_t need = ((size_t)40 << 20) + 16384;  // x16 16MB | w16 24MB | bias 16KB
    if (ws_size < need) {
        gemm_f32_fallback<<<dim3(BROWS, NMOD), dim3(256), 0, stream>>>(x, W, lf, gf, st, clk, out);
        return;
    }

    f16*   x16  = (f16*)d_ws;
    f16*   w16  = (f16*)((char*)d_ws + ((size_t)16 << 20));
    float* bias = (float*)((char*)d_ws + ((size_t)40 << 20));

    cvt_f32_f16<<<dim3(8192),  dim3(256), 0, stream>>>(x, x16, 8388608 / 4);
    cvt_f32_f16<<<dim3(12288), dim3(256), 0, stream>>>(W, w16, 12582912 / 4);
    bias_kernel<<<dim3(NMOD), dim3(1024), 0, stream>>>(lf, gf, st, clk, bias);
    gemm_kernel<<<dim3(512), dim3(256), 0, stream>>>(x16, w16, bias, out);
}

// Round 7
// 202.432 us; speedup vs baseline: 1.0057x; 1.0057x over previous
//
#include <hip/hip_runtime.h>
#include <cstdint>
#include <cstddef>

// ---------------------------------------------------------------------------
// AxonalConnections: out[d] = sum_{s != d} x[s] @ W[p(s,d)]^T + bias[d]
//   x: [4, 2048, 1024] f32, W: [12, 1024, 1024] f32 (row o = out-dim)
//   bias[d][o] = strength[d]*(sin(t*lf[d][o]) + sin(t*gf[d])), t = 2pi*clk*1e-3
// R6 == R3 (resubmit; five GPU timeouts running — no new blind deltas).
//     fp16 MFMA grouped GEMM. 128x64 tile (1024 blocks = 4/CU), BK=32,
//     4 waves (2x2, wave = 64x32), double-buffered LDS, T2 XOR swizzle
//     (both-sides involution), bias fused in epilogue, single merged cvt.
// ---------------------------------------------------------------------------

typedef _Float16 f16;
typedef _Float16 f16x8 __attribute__((ext_vector_type(8)));
typedef _Float16 f16x4 __attribute__((ext_vector_type(4)));
typedef float    f32x4 __attribute__((ext_vector_type(4)));

#define NMOD  4
#define BROWS 2048
#define DDIM  1024
#define BK    32
#define NT    96   // 3 src panels x 32 K-steps of BK=32

// ---- fused fp32 -> fp16 conversion: x (16MB out) then W (24MB out) ----
// x16 occupies ws[0,16MB) exactly (8,388,608 f16), w16 follows -> one out index.
__global__ void cvt_all(const float* __restrict__ x, const float* __restrict__ W,
                        f16* __restrict__ out16) {
    int i = blockIdx.x * blockDim.x + threadIdx.x;   // float4 index, 5,242,880 total
    const int nx4 = 8388608 / 4;
    float4 v;
    if (i < nx4) v = reinterpret_cast<const float4*>(x)[i];
    else         v = reinterpret_cast<const float4*>(W)[i - nx4];
    f16x4 h = { (f16)v.x, (f16)v.y, (f16)v.z, (f16)v.w };
    reinterpret_cast<f16x4*>(out16)[i] = h;
}

__device__ __forceinline__ void g2l16(const f16* g, f16* l) {
    // global -> LDS direct, 16B/lane; LDS dest is wave-uniform base (HW adds lane*16)
    __builtin_amdgcn_global_load_lds(
        (const __attribute__((address_space(1))) void*)g,
        (__attribute__((address_space(3))) void*)l,
        16, 0, 0);
}

// A tile: 128x32 f16 = 512 16B-slots; B tile: 64x32 = 256 slots.
// Involution on slot index: f(s) = s ^ ((s>>3)&7) (operand bits 3-5 -> bits 0-2).
// Stage: lane writes physical slot p = w*64+l linearly (global_load_lds is
// lane-linear); it FETCHES the global chunk of logical slot f(p).
// Read: logical slot s is read at physical f(s). f(f(s)) = s.
// Conflict fix: the 8 lanes with equal (fr&1, fq) and varying fr>>1 (previously
// same bank group, 8-way) now map to 8 distinct bank groups (XOR injective).
__global__ __launch_bounds__(256, 4)
void gemm_kernel(const f16* __restrict__ X,     // [4, 2048, 1024] f16
                 const f16* __restrict__ Wh,    // [12, 1024, 1024] f16 (o-major)
                 const float* __restrict__ lf,  // [4,1024]
                 const float* __restrict__ gf,  // [4]
                 const float* __restrict__ st,  // [4]
                 const int*  __restrict__ clk,
                 float* __restrict__ out) {     // [4, 2048, 1024] f32
    __shared__ f16 As[2][128 * BK];   // 2 x 8 KB
    __shared__ f16 Bs[2][64 * BK];    // 2 x 4 KB

    // 1024 blocks: XCD-aware swizzle (1024 % 8 == 0 -> bijective).
    // XCD x (= bid%8) gets contiguous swz chunk [x*128, (x+1)*128).
    const int bid = blockIdx.x;
    const int swz = ((bid & 7) << 7) | (bid >> 3);
    const int d  = swz >> 8;                 // dst module 0..3
    const int m0 = ((swz >> 4) & 15) << 7;   // M tile origin (16 tiles of 128)
    const int n0 = (swz & 15) << 6;          // N tile origin (16 tiles of 64)

    const int t  = threadIdx.x;
    const int l  = t & 63;
    const int w  = t >> 6;            // wave 0..3
    const int wr = w >> 1;            // wave row (M: 0..1, 64 rows each)
    const int wc = w & 1;             // wave col (N: 0..1, 32 cols each)
    const int fr = l & 15;
    const int fq = l >> 4;

    // ---- staging source geometry (inverse-swizzled global address) ----
    // physical slot within a 256-slot group: p = w*64 + l; logical g = f(p)
    const int g    = (w * 64 + l) ^ ((l >> 3) & 7);
    const int srow = g >> 2;          // 0..63
    const int scol = (g & 3) << 3;    // f16 col offset 0,8,16,24

    // ---- read-side swizzle (constant per lane): XOR slot bits 0-2 by fr>>1 ----
    const int arx = (fr >> 1) << 3;   // f16-index XOR (= byte XOR (fr>>1)<<4)

    f32x4 acc[4][2] = {};

    auto stage = [&](int b, int tt) {
        const int j  = tt >> 5;                     // src panel 0..2 (uniform)
        const int k0 = (tt & 31) << 5;              // K offset within panel
        const int s  = j + (j >= d ? 1 : 0);        // src module (skip d)
        const int p  = s * 3 + d - (d > s ? 1 : 0); // index in PAIRS order
        const f16* xa = X  + ((size_t)s * BROWS + m0 + srow) * DDIM + k0 + scol;
        const f16* xb = Wh + ((size_t)p * DDIM  + n0 + srow) * DDIM + k0 + scol;
        f16* lA = &As[b][w << 9];                   // wave-uniform: slot w*64, 512 f16
        f16* lB = &Bs[b][w << 9];
        g2l16(xa,                     lA);          // A rows 0..63   (q=0)
        g2l16(xa + (size_t)64 * DDIM, lA + 2048);   // A rows 64..127 (q=1, +256 slots)
        g2l16(xb,                     lB);          // B rows 0..63
    };

    auto compute = [&](int b) {
        f16x8 af[4], bf[2];
        #pragma unroll
        for (int m = 0; m < 4; ++m)
            af[m] = *reinterpret_cast<const f16x8*>(
                &As[b][(((wr * 64 + m * 16 + fr) * BK) + fq * 8) ^ arx]);
        #pragma unroll
        for (int n = 0; n < 2; ++n)
            bf[n] = *reinterpret_cast<const f16x8*>(
                &Bs[b][(((wc * 32 + n * 16 + fr) * BK) + fq * 8) ^ arx]);
        #pragma unroll
        for (int m = 0; m < 4; ++m)
            #pragma unroll
            for (int n = 0; n < 2; ++n)
                acc[m][n] = __builtin_amdgcn_mfma_f32_16x16x32_f16(af[m], bf[n], acc[m][n], 0, 0, 0);
    };

    stage(0, 0);
    __syncthreads();                 // vmcnt(0) drained -> buf0 ready

    #pragma unroll 1
    for (int tt = 0; tt < NT - 2; tt += 2) {
        stage(1, tt + 1);
        compute(0);
        __syncthreads();             // buf1 ready; all waves done with buf0
        stage(0, tt + 2);
        compute(1);
        __syncthreads();             // buf0 ready; all waves done with buf1
    }
    stage(1, NT - 1);
    compute(0);
    __syncthreads();
    compute(1);

    // ---- epilogue: fused bias; C col = lane&15, row = (lane>>4)*4 + reg ----
    const int c0 = n0 + wc * 32 + fr;
    const int r0 = m0 + wr * 64 + fq * 4;
    const float tt_ = (float)(6.283185307179586 * 0.001 * (double)(*clk));
    const float sd  = st[d];
    const float sgf = sinf(tt_ * gf[d]);
    float* od = out + (size_t)d * BROWS * DDIM;
    #pragma unroll
    for (int n = 0; n < 2; ++n) {
        const float bv = sd * (sinf(tt_ * lf[d * DDIM + c0 + n * 16]) + sgf);
        #pragma unroll
        for (int m = 0; m < 4; ++m) {
            #pragma unroll
            for (int r = 0; r < 4; ++r) {
                od[(size_t)(r0 + m * 16 + r) * DDIM + (c0 + n * 16)] = acc[m][n][r] + bv;
            }
        }
    }
}

// ---- insurance fallback (only if ws_size too small for the fp16 path) ----
__global__ __launch_bounds__(256)
void gemm_f32_fallback(const float* __restrict__ X, const float* __restrict__ W,
                       const float* __restrict__ lf, const float* __restrict__ gf,
                       const float* __restrict__ st, const int* __restrict__ clk,
                       float* __restrict__ out) {
    const int d = blockIdx.y;
    const int b = blockIdx.x;
    __shared__ float xs[3][DDIM];
    for (int j = 0; j < 3; ++j) {
        int s = j + (j >= d ? 1 : 0);
        for (int i = threadIdx.x; i < DDIM; i += 256)
            xs[j][i] = X[((size_t)s * BROWS + b) * DDIM + i];
    }
    __syncthreads();
    float t = (float)(6.283185307179586 * 0.001 * (double)(*clk));
    for (int oi = 0; oi < 4; ++oi) {
        int o = threadIdx.x + oi * 256;
        float acc = 0.f;
        for (int j = 0; j < 3; ++j) {
            int s = j + (j >= d ? 1 : 0);
            int p = s * 3 + d - (d > s ? 1 : 0);
            const float* wrow = W + ((size_t)p * DDIM + o) * DDIM;
            float a = 0.f;
            for (int k = 0; k < DDIM; k += 4) {
                float4 wv = *reinterpret_cast<const float4*>(wrow + k);
                a += xs[j][k] * wv.x + xs[j][k + 1] * wv.y
                   + xs[j][k + 2] * wv.z + xs[j][k + 3] * wv.w;
            }
            acc += a;
        }
        out[((size_t)d * BROWS + b) * DDIM + o] =
            acc + st[d] * (sinf(t * lf[d * DDIM + o]) + sinf(t * gf[d]));
    }
}

extern "C" void kernel_launch(void* const* d_in, const int* in_sizes, int n_in,
                              void* d_out, int out_size, void* d_ws, size_t ws_size,
                              hipStream_t stream) {
    const float* x  = (const float*)d_in[0];   // [4,2048,1024]
    const float* W  = (const float*)d_in[1];   // [12,1024,1024]
    const float* lf = (const float*)d_in[2];   // [4,1024]
    const float* gf = (const float*)d_in[3];   // [4]
    const float* st = (const float*)d_in[4];   // [4]
    const int*  clk = (const int*)d_in[5];     // scalar
    float* out = (float*)d_out;

    const size_t need = (size_t)40 << 20;      // x16 16MB | w16 24MB
    if (ws_size < need) {
        gemm_f32_fallback<<<dim3(BROWS, NMOD), dim3(256), 0, stream>>>(x, W, lf, gf, st, clk, out);
        return;
    }

    f16* x16 = (f16*)d_ws;                     // w16 = x16 + 8,388,608 (at +16MB)
    f16* w16 = (f16*)((char*)d_ws + ((size_t)16 << 20));

    cvt_all<<<dim3(20480), dim3(256), 0, stream>>>(x, W, x16);
    gemm_kernel<<<dim3(1024), dim3(256), 0, stream>>>(x16, w16, lf, gf, st, clk, out);
}